// Round 1
// 833.877 us; speedup vs baseline: 1.0811x; 1.0811x over previous
//
#include <hip/hip_runtime.h>

// Encoder block: LN1 -> QKV -> per-token head-mix attention -> scramble ->
// WO -> +x,LN1 -> W1+GELU (2 halves) -> W2 accum (+b2,+q2) -> LN2 in-place.
//
// GEMM rewritten to the 256x256 8-wave pipelined schedule (T1..T5):
//   - tile 256x256, BK=64, 512 thr = 8 waves (2M x 4N), wave tile 128x64,
//     mfma_f32_16x16x32_bf16, acc = f32x4[8][4] (128 regs/lane).
//   - LDS 128 KiB dynamic: A,B each 2x (256x64 bf16 = 32 KB) double buffer.
//   - 4 phases per K-tile: {ds_read frags | stage 1 half-tile (2x
//     global_load_lds dwordx4) | barrier | lgkmcnt(0) | setprio(1) | 16 MFMA
//     | setprio(0) | barrier}. B(nh0) frags stay register-resident so phase 4
//     has zero ds_reads and every LDS region is overwritten only >=1 full
//     barrier after its last read completed (race-free by construction):
//       ph1: stage A-high(u+1)   (A[u+1] buf free since tile u-1 ph3)
//       ph2: stage B-high(u+1)   (B[u+1] buf free since tile u-1 ph2)
//       ph3: stage B-low(u+2)    (cur B reads done at ph2 barrier)
//       ph4: stage A-low(u+2)    (cur A reads done at ph3 barrier)
//     counted s_waitcnt vmcnt(4) once per K-tile (2 half-tiles in flight
//     across the tile boundary; vmcnt(0) only at the tail).
//   - chunk swizzle: 16B chunk c of row r lives at slot c^(r&7); staging
//     keeps LDS linear (global source pre-swizzled per lane); ds_read_b128
//     frag reads are 2-way (free) per 16-lane quarter.
//   - XCD-aware bijective block swizzle (all grids % 8 == 0).
// Workspace footprint: 152 MB (d_out doubles as the f32 residual buffer).

typedef __attribute__((ext_vector_type(8))) short s16x8;
typedef __attribute__((ext_vector_type(4))) short s16x4;
typedef __attribute__((ext_vector_type(4))) float f32x4;

__device__ __forceinline__ short f2bf(float x) {
  unsigned u = __builtin_bit_cast(unsigned, x);
  u = (u + 0x7FFFu + ((u >> 16) & 1u)) >> 16;
  return (short)u;
}
__device__ __forceinline__ float bf2f(short s) {
  unsigned u = ((unsigned)(unsigned short)s) << 16;
  return __builtin_bit_cast(float, u);
}

__device__ __forceinline__ void ld_g2l16(const short* g, short* l) {
  __builtin_amdgcn_global_load_lds(
      (const __attribute__((address_space(1))) void*)g,
      (__attribute__((address_space(3))) void*)l, 16, 0, 0);
}

// Fast GELU (tanh form via v_exp_f32; |err| ~1e-3 << bf16 noise).
__device__ __forceinline__ float fast_gelu(float v) {
  float y = 0.7978845608f * (v + 0.044715f * v * v * v);
  float ay = fabsf(y);
  float t = __expf(-2.0f * ay);
  float th = (1.0f - t) * __frcp_rn(1.0f + t);
  th = (y >= 0.f) ? th : -th;
  return 0.5f * v * (1.0f + th);
}

#define MFMA16(va, vb, vc) \
  __builtin_amdgcn_mfma_f32_16x16x32_bf16(va, vb, vc, 0, 0, 0)

// ---------------------------------------------------------------------------
// GEMM: C[M,N] = A[M,K] @ BT[N,K]^T  (A, BT bf16 row-major, K-contiguous).
// M is always 16384 (64 M-tiles, hardcoded). N,K multiples of 256.
// EPI: 0 = store bf16; 1 = store f32; 2 = +bias, fast GELU, store bf16;
//      4 = out += acc (+bias if non-null), f32 in-place accumulate.
// Launch: grid = 64*(N/256) blocks x 512 thr, dynamic LDS = 131072 B.
// ---------------------------------------------------------------------------
template <int EPI>
__global__ __launch_bounds__(512, 2) void gemm256(
    const short* __restrict__ A, const short* __restrict__ BT,
    void* __restrict__ outp, const float* __restrict__ bias, int N, int K) {
  extern __shared__ __align__(16) short smem[];

  const int t = threadIdx.x;
  const int lane = t & 63, w = t >> 6;
  const int wm = w >> 2, wn = w & 3;  // wave tile: rows wm*128, cols wn*64

  // XCD-aware bijective swizzle (gridDim.x % 8 == 0 for all our launches);
  // consecutive wg within an XCD chunk share bn (B panel stays in that L2).
  const int nwg = gridDim.x, q8 = nwg >> 3;
  const int wg = ((int)blockIdx.x & 7) * q8 + ((int)blockIdx.x >> 3);
  const int bm = wg & 63;  // M = 16384 -> 64 M-tiles
  const int bn = wg >> 6;

  short* Ac = smem;           // A buffers: 2 x 16384 shorts (32 KB each)
  short* An = smem + 16384;
  short* Bc = smem + 32768;   // B buffers
  short* Bn = smem + 49152;

  // Staging: linear LDS slot s = q*512 + w*64 + lane covers
  // (row = h*128 + q*64 + w*8 + (lane>>3), slot = lane&7); the global chunk
  // fetched into that slot is pre-swizzled: c = (lane&7) ^ ((lane>>3)&7).
  const int l8 = lane >> 3;
  const int lcw = ((lane & 7) ^ l8) * 8;  // swizzled chunk offset (shorts)
  const short* gA = A + (size_t)(bm * 256 + w * 8 + l8) * K + lcw;
  const short* gB = BT + (size_t)(bn * 256 + w * 8 + l8) * K + lcw;
  const int lb = w * 512;  // wave's LDS base within a (half,q) block

  auto stage = [&](const short* g, short* buf, int h, int kt) {
    const size_t go = (size_t)(h * 128) * K + (size_t)kt * 64;
    ld_g2l16(g + go, buf + h * 8192 + lb);                   // q = 0
    ld_g2l16(g + go + (size_t)64 * K, buf + h * 8192 + 4096 + lb);  // q = 1
  };

  // Fragment reads: row r, chunk c=(ks*4+fc) at slot c^(r&7); r&7 == fr&7.
  const int fr = lane & 15, fc = lane >> 4;
  const int baseA = (wm * 128 + fr) * 64;
  const int baseB = (wn * 64 + fr) * 64;
  const int sl0 = (fc ^ (fr & 7)) * 8;
  const int sl1 = ((4 + fc) ^ (fr & 7)) * 8;

  f32x4 acc[8][4];
#pragma unroll
  for (int m = 0; m < 8; ++m)
#pragma unroll
    for (int n = 0; n < 4; ++n) acc[m][n] = (f32x4){0.f, 0.f, 0.f, 0.f};

  s16x8 a[4][2], b0[2][2], b1[2][2];

  const int nt = K >> 6;

  // Prologue: tile0 all 4 halves; tile1 A-low + B-low (steady-state shape).
  stage(gA, Ac, 0, 0);
  stage(gA, Ac, 1, 0);
  stage(gB, Bc, 0, 0);
  stage(gB, Bc, 1, 0);
  if (nt > 1) {
    stage(gA, An, 0, 1);
    stage(gB, Bn, 0, 1);
    asm volatile("s_waitcnt vmcnt(4)" ::: "memory");  // tile0 landed
  } else {
    asm volatile("s_waitcnt vmcnt(0)" ::: "memory");
  }
  __builtin_amdgcn_s_barrier();
  asm volatile("" ::: "memory");

  for (int u = 0; u < nt; ++u) {
    // ---- phase 1: read A(mh0) + B(nh0); stage A-high(u+1)
#pragma unroll
    for (int mi = 0; mi < 4; ++mi) {
      a[mi][0] = *(const s16x8*)(Ac + baseA + mi * 1024 + sl0);
      a[mi][1] = *(const s16x8*)(Ac + baseA + mi * 1024 + sl1);
    }
#pragma unroll
    for (int ni = 0; ni < 2; ++ni) {
      b0[ni][0] = *(const s16x8*)(Bc + baseB + ni * 1024 + sl0);
      b0[ni][1] = *(const s16x8*)(Bc + baseB + ni * 1024 + sl1);
    }
    if (u + 1 < nt) stage(gA, An, 1, u + 1);
    __builtin_amdgcn_s_barrier();
    asm volatile("s_waitcnt lgkmcnt(0)" ::: "memory");
    __builtin_amdgcn_s_setprio(1);
#pragma unroll
    for (int mi = 0; mi < 4; ++mi)
#pragma unroll
      for (int ni = 0; ni < 2; ++ni) {
        acc[mi][ni] = MFMA16(a[mi][0], b0[ni][0], acc[mi][ni]);
        acc[mi][ni] = MFMA16(a[mi][1], b0[ni][1], acc[mi][ni]);
      }
    __builtin_amdgcn_s_setprio(0);
    __builtin_amdgcn_s_barrier();
    asm volatile("" ::: "memory");

    // ---- phase 2: read B(nh1); stage B-high(u+1)
#pragma unroll
    for (int ni = 0; ni < 2; ++ni) {
      b1[ni][0] = *(const s16x8*)(Bc + baseB + 2048 + ni * 1024 + sl0);
      b1[ni][1] = *(const s16x8*)(Bc + baseB + 2048 + ni * 1024 + sl1);
    }
    if (u + 1 < nt) stage(gB, Bn, 1, u + 1);
    __builtin_amdgcn_s_barrier();
    asm volatile("s_waitcnt lgkmcnt(0)" ::: "memory");
    __builtin_amdgcn_s_setprio(1);
#pragma unroll
    for (int mi = 0; mi < 4; ++mi)
#pragma unroll
      for (int ni = 0; ni < 2; ++ni) {
        acc[mi][2 + ni] = MFMA16(a[mi][0], b1[ni][0], acc[mi][2 + ni]);
        acc[mi][2 + ni] = MFMA16(a[mi][1], b1[ni][1], acc[mi][2 + ni]);
      }
    __builtin_amdgcn_s_setprio(0);
    __builtin_amdgcn_s_barrier();
    asm volatile("" ::: "memory");

    // ---- phase 3: read A(mh1); stage B-low(u+2) into current B buffer
#pragma unroll
    for (int mi = 0; mi < 4; ++mi) {
      a[mi][0] = *(const s16x8*)(Ac + baseA + 4096 + mi * 1024 + sl0);
      a[mi][1] = *(const s16x8*)(Ac + baseA + 4096 + mi * 1024 + sl1);
    }
    if (u + 2 < nt) stage(gB, Bc, 0, u + 2);
    __builtin_amdgcn_s_barrier();
    asm volatile("s_waitcnt lgkmcnt(0)" ::: "memory");
    __builtin_amdgcn_s_setprio(1);
#pragma unroll
    for (int mi = 0; mi < 4; ++mi)
#pragma unroll
      for (int ni = 0; ni < 2; ++ni) {
        acc[4 + mi][2 + ni] = MFMA16(a[mi][0], b1[ni][0], acc[4 + mi][2 + ni]);
        acc[4 + mi][2 + ni] = MFMA16(a[mi][1], b1[ni][1], acc[4 + mi][2 + ni]);
      }
    __builtin_amdgcn_s_setprio(0);
    __builtin_amdgcn_s_barrier();
    asm volatile("" ::: "memory");

    // ---- phase 4: (mh1,nh0) all from registers; stage A-low(u+2);
    //      counted vmcnt before the tile-boundary barrier.
    if (u + 2 < nt) stage(gA, Ac, 0, u + 2);
    __builtin_amdgcn_s_setprio(1);
#pragma unroll
    for (int mi = 0; mi < 4; ++mi)
#pragma unroll
      for (int ni = 0; ni < 2; ++ni) {
        acc[4 + mi][ni] = MFMA16(a[mi][0], b0[ni][0], acc[4 + mi][ni]);
        acc[4 + mi][ni] = MFMA16(a[mi][1], b0[ni][1], acc[4 + mi][ni]);
      }
    __builtin_amdgcn_s_setprio(0);
    if (u + 2 < nt) {
      asm volatile("s_waitcnt vmcnt(4)" ::: "memory");  // tile u+1 landed
    } else {
      asm volatile("s_waitcnt vmcnt(0)" ::: "memory");  // tail drain
    }
    __builtin_amdgcn_s_barrier();
    asm volatile("" ::: "memory");

    short* tp = Ac; Ac = An; An = tp;
    tp = Bc; Bc = Bn; Bn = tp;
  }

  // Epilogue. 16x16 C/D layout: col = lane&15, row = (lane>>4)*4 + r.
  const int mb = bm * 256 + wm * 128;
  const int nb = bn * 256 + wn * 64;
  const int cr = (lane >> 4) * 4;
  const int cc = lane & 15;
#pragma unroll
  for (int m = 0; m < 8; ++m) {
#pragma unroll
    for (int n = 0; n < 4; ++n) {
#pragma unroll
      for (int r = 0; r < 4; ++r) {
        const size_t row = (size_t)(mb + m * 16 + cr + r);
        const size_t col = (size_t)(nb + n * 16 + cc);
        float v = acc[m][n][r];
        if constexpr (EPI == 0) {
          ((short*)outp)[row * N + col] = f2bf(v);
        } else if constexpr (EPI == 1) {
          ((float*)outp)[row * N + col] = v;
        } else if constexpr (EPI == 2) {
          v += bias[col];
          ((short*)outp)[row * N + col] = f2bf(fast_gelu(v));
        } else {  // EPI == 4
          float prev = ((float*)outp)[row * N + col];
          v += prev;
          if (bias) v += bias[col];
          ((float*)outp)[row * N + col] = v;
        }
      }
    }
  }
}

// ---------------------------------------------------------------------------
// Row LayerNorm over D=1024. Optional fp32 `add` (residual). Writes fp32
// and/or bf16. One block (256 thr) per row. Safe in-place (outf == in).
// ---------------------------------------------------------------------------
__global__ __launch_bounds__(256) void ln_k(
    const float* __restrict__ in, const float* __restrict__ add,
    const float* __restrict__ g, const float* __restrict__ b,
    float* __restrict__ outf, short* __restrict__ outb) {
  const int row = blockIdx.x;
  const size_t off = (size_t)row * 1024;
  const int t = threadIdx.x;
  float4 v = ((const float4*)(in + off))[t];
  if (add) {
    float4 w = ((const float4*)(add + off))[t];
    v.x += w.x; v.y += w.y; v.z += w.z; v.w += w.w;
  }
  float s = v.x + v.y + v.z + v.w;
  float ss = v.x * v.x + v.y * v.y + v.z * v.z + v.w * v.w;
#pragma unroll
  for (int o = 32; o > 0; o >>= 1) {
    s += __shfl_xor(s, o, 64);
    ss += __shfl_xor(ss, o, 64);
  }
  __shared__ float ps[4], pss[4];
  const int lane = t & 63, wave = t >> 6;
  if (lane == 0) { ps[wave] = s; pss[wave] = ss; }
  __syncthreads();
  s = ps[0] + ps[1] + ps[2] + ps[3];
  ss = pss[0] + pss[1] + pss[2] + pss[3];
  const float mean = s * (1.0f / 1024.0f);
  const float var = ss * (1.0f / 1024.0f) - mean * mean;
  const float rstd = rsqrtf(var + 1e-6f);
  const float4 gv = ((const float4*)g)[t];
  const float4 bv = ((const float4*)b)[t];
  float4 o4;
  o4.x = (v.x - mean) * rstd * gv.x + bv.x;
  o4.y = (v.y - mean) * rstd * gv.y + bv.y;
  o4.z = (v.z - mean) * rstd * gv.z + bv.z;
  o4.w = (v.w - mean) * rstd * gv.w + bv.w;
  if (outf) ((float4*)(outf + off))[t] = o4;
  if (outb) {
    s16x4 ob;
    ob[0] = f2bf(o4.x); ob[1] = f2bf(o4.y);
    ob[2] = f2bf(o4.z); ob[3] = f2bf(o4.w);
    *(s16x4*)(outb + off + t * 4) = ob;
  }
}

// ---------------------------------------------------------------------------
// Weight convert+transpose: W[K,N] fp32 -> WT[N,K] bf16. 32x32 tiles.
// ---------------------------------------------------------------------------
__global__ __launch_bounds__(256) void wconv_t(const float* __restrict__ W,
                                               short* __restrict__ WT, int K,
                                               int N) {
  __shared__ float tile[32][33];
  const int t = threadIdx.x;
  const int c = t & 31, r = t >> 5;
  const int n0 = blockIdx.x * 32, k0 = blockIdx.y * 32;
#pragma unroll
  for (int rr = r; rr < 32; rr += 8)
    tile[rr][c] = W[(size_t)(k0 + rr) * N + n0 + c];
  __syncthreads();
#pragma unroll
  for (int rr = r; rr < 32; rr += 8)
    WT[(size_t)(n0 + rr) * K + k0 + c] = f2bf(tile[c][rr]);
}

// ---------------------------------------------------------------------------
// Per-token head-mixing attention + faithful-reshape scramble.
// ---------------------------------------------------------------------------
__global__ __launch_bounds__(256) void attn_k(const short* __restrict__ qkv,
                                              short* __restrict__ omix) {
  __shared__ float Qs[4][16][64];
  __shared__ float Ks[4][16][64];
  __shared__ float Vs[4][16][64];
  __shared__ float Ps[4][16][16];
  const int lane = threadIdx.x & 63;
  const int wave = threadIdx.x >> 6;
  const int tok = blockIdx.x * 4 + wave;
  const short* base = qkv + (size_t)tok * 3072;

#pragma unroll
  for (int half = 0; half < 2; half++) {
    const int e = half * 512 + lane * 8;
    const int h = e >> 6, d = e & 63;
    s16x8 rq = *(const s16x8*)(base + e);
    s16x8 rk = *(const s16x8*)(base + 1024 + e);
    s16x8 rv = *(const s16x8*)(base + 2048 + e);
#pragma unroll
    for (int j = 0; j < 8; j++) {
      Qs[wave][h][d + j] = bf2f(rq[j]);
      Ks[wave][h][d + j] = bf2f(rk[j]);
      Vs[wave][h][d + j] = bf2f(rv[j]);
    }
  }
  __syncthreads();

  const int h = lane & 15;
  const int g0 = (lane >> 4) * 4;
  float sc[4] = {0.f, 0.f, 0.f, 0.f};
  for (int d = 0; d < 64; d++) {
    const float qv = Qs[wave][h][d];
#pragma unroll
    for (int i = 0; i < 4; i++) sc[i] += qv * Ks[wave][g0 + i][d];
  }
#pragma unroll
  for (int i = 0; i < 4; i++) sc[i] *= 0.125f;
  float m = fmaxf(fmaxf(sc[0], sc[1]), fmaxf(sc[2], sc[3]));
  m = fmaxf(m, __shfl_xor(m, 16, 64));
  m = fmaxf(m, __shfl_xor(m, 32, 64));
  float e[4], sum = 0.f;
#pragma unroll
  for (int i = 0; i < 4; i++) { e[i] = __expf(sc[i] - m); sum += e[i]; }
  sum += __shfl_xor(sum, 16, 64);
  sum += __shfl_xor(sum, 32, 64);
  const float inv = __frcp_rn(sum);
#pragma unroll
  for (int i = 0; i < 4; i++) Ps[wave][h][g0 + i] = e[i] * inv;
  __syncthreads();

  const int d0 = (lane >> 4) * 16;
  float o[16];
#pragma unroll
  for (int dd = 0; dd < 16; dd++) o[dd] = 0.f;
  for (int gg = 0; gg < 16; gg++) {
    const float pv = Ps[wave][h][gg];
#pragma unroll
    for (int dd = 0; dd < 16; dd++) o[dd] += pv * Vs[wave][gg][d0 + dd];
  }

  const int b = tok >> 12, t = tok & 4095;
  const size_t dst =
      ((size_t)(b * 4096 + h * 256 + (t >> 4))) * 1024 + (t & 15) * 64 + d0;
  s16x8 w0, w1;
#pragma unroll
  for (int j = 0; j < 8; j++) { w0[j] = f2bf(o[j]); w1[j] = f2bf(o[8 + j]); }
  *(s16x8*)(omix + dst) = w0;
  *(s16x8*)(omix + dst + 8) = w1;
}

// ---------------------------------------------------------------------------
extern "C" void kernel_launch(void* const* d_in, const int* in_sizes, int n_in,
                              void* d_out, int out_size, void* d_ws,
                              size_t ws_size, hipStream_t stream) {
  const float* x    = (const float*)d_in[0];
  const float* wq   = (const float*)d_in[1];
  const float* wk   = (const float*)d_in[2];
  const float* wv   = (const float*)d_in[3];
  const float* wo   = (const float*)d_in[4];
  const float* ln1g = (const float*)d_in[5];
  const float* ln1b = (const float*)d_in[6];
  const float* w1   = (const float*)d_in[7];
  const float* b1   = (const float*)d_in[8];
  const float* w2   = (const float*)d_in[9];
  const float* b2   = (const float*)d_in[10];
  const float* ln2g = (const float*)d_in[11];
  const float* ln2b = (const float*)d_in[12];
  float* out = (float*)d_out;  // [16384,1024] f32; doubles as o2/q2 buffer

  char* ws = (char*)d_ws;
  const size_t MB = 1024ull * 1024ull;
  const size_t NEEDED = 152 * MB;
  if (ws_size < NEEDED) return;  // fail-numeric instead of page-fault

  short* QKV  = (short*)(ws + 0);        // phase1 [16384,3072] bf16
  short* Q2B  = (short*)(ws + 0);        // phase2 [16384,1024] bf16
  short* Hbuf = (short*)(ws + 32 * MB);  // phase2 [16384,2048] bf16
  short* X1 = (short*)(ws + 96 * MB);    // x1, then o_mixed bf16
  short* WQKVT = (short*)(ws + 128 * MB);
  short* WOT   = (short*)(ws + 134 * MB);
  short* W1T   = (short*)(ws + 136 * MB);
  short* W2aT  = (short*)(ws + 144 * MB);
  short* W2bT  = (short*)(ws + 148 * MB);

  const dim3 B256(256);
  const dim3 B512(512);
  const unsigned LDS = 131072;  // 128 KiB dynamic LDS for gemm256

  static bool attr_done = false;
  if (!attr_done) {
    attr_done = true;
    void (*k0)(const short*, const short*, void*, const float*, int, int) =
        gemm256<0>;
    void (*k1)(const short*, const short*, void*, const float*, int, int) =
        gemm256<1>;
    void (*k2)(const short*, const short*, void*, const float*, int, int) =
        gemm256<2>;
    void (*k4)(const short*, const short*, void*, const float*, int, int) =
        gemm256<4>;
    (void)hipFuncSetAttribute((const void*)k0,
        hipFuncAttributeMaxDynamicSharedMemorySize, (int)LDS);
    (void)hipFuncSetAttribute((const void*)k1,
        hipFuncAttributeMaxDynamicSharedMemorySize, (int)LDS);
    (void)hipFuncSetAttribute((const void*)k2,
        hipFuncAttributeMaxDynamicSharedMemorySize, (int)LDS);
    (void)hipFuncSetAttribute((const void*)k4,
        hipFuncAttributeMaxDynamicSharedMemorySize, (int)LDS);
  }

  wconv_t<<<dim3(32, 32), B256, 0, stream>>>(wq, WQKVT, 1024, 1024);
  wconv_t<<<dim3(32, 32), B256, 0, stream>>>(wk, WQKVT + 1024 * 1024, 1024, 1024);
  wconv_t<<<dim3(32, 32), B256, 0, stream>>>(wv, WQKVT + 2048 * 1024, 1024, 1024);
  wconv_t<<<dim3(32, 32), B256, 0, stream>>>(wo, WOT, 1024, 1024);
  wconv_t<<<dim3(128, 32), B256, 0, stream>>>(w1, W1T, 1024, 4096);
  wconv_t<<<dim3(32, 64), B256, 0, stream>>>(w2, W2aT, 2048, 1024);
  wconv_t<<<dim3(32, 64), B256, 0, stream>>>(w2 + 2048 * 1024, W2bT, 2048, 1024);

  // x1 = LN1(x) -> bf16
  ln_k<<<16384, B256, 0, stream>>>(x, nullptr, ln1g, ln1b, nullptr, X1);

  // QKV = x1 @ [wq|wk|wv]   (grid 64 x 12 = 768 blocks)
  gemm256<0><<<dim3(768), B512, LDS, stream>>>(X1, WQKVT, QKV, nullptr,
                                               3072, 1024);

  // attention + scramble -> o_mixed (reuses X1 region)
  attn_k<<<4096, B256, 0, stream>>>(QKV, X1);

  // o2 = o_mixed @ wo -> f32 into d_out   (64 x 4 = 256 blocks)
  gemm256<1><<<dim3(256), B512, LDS, stream>>>(X1, WOT, out, nullptr,
                                               1024, 1024);

  // q2 = LN1(o2 + x): f32 in-place in d_out, bf16 copy in Q2B
  ln_k<<<16384, B256, 0, stream>>>(out, x, ln1g, ln1b, out, Q2B);

  // FFN half A  (W1: 64 x 8 = 512 blocks; W2: 256 blocks)
  gemm256<2><<<dim3(512), B512, LDS, stream>>>(Q2B, W1T, Hbuf, b1,
                                               2048, 1024);
  gemm256<4><<<dim3(256), B512, LDS, stream>>>(Hbuf, W2aT, out, nullptr,
                                               1024, 2048);

  // FFN half B
  gemm256<2><<<dim3(512), B512, LDS, stream>>>(Q2B, W1T + 2048 * 1024, Hbuf,
                                               b1 + 2048, 2048, 1024);
  gemm256<4><<<dim3(256), B512, LDS, stream>>>(Hbuf, W2bT, out, b2,
                                               1024, 2048);

  // out = LN2(y) in-place
  ln_k<<<16384, B256, 0, stream>>>(out, nullptr, ln2g, ln2b, out, nullptr);
}

// Round 3
// 828.482 us; speedup vs baseline: 1.0882x; 1.0065x over previous
//
#include <hip/hip_runtime.h>

// Encoder block: LN1 -> QKV -> per-token head-mix attention -> scramble ->
// WO -> +x,LN1 -> W1+GELU (2 halves) -> W2 accum (+b2,+q2) -> LN2 in-place.
//
// GEMM: 256x256 8-wave pipelined schedule, revision 3 (race-fixed deep ring):
//   - tile 256x256, BK=64, 512 thr = 8 waves (2M x 4N), wave tile 128x64,
//     mfma_f32_16x16x32_bf16, acc = f32x4[8][4].
//   - LDS 128 KiB dynamic: A,B double-buffered (2 x 32 KB each).
//   - Staging halves h0/h1 are ROW ranges 0-127/128-255. Wave (wm,wn) reads
//     ONLY its own halves: A-half wm in ph1 AND ph3; B-half (wn>>1) in ph1
//     AND ph2. So the entire B region's last read retires at ph2-end
//     barrier, A region's at ph3-end barrier. Safe deep ring staging of
//     tile u+2 into the CURRENT-parity buffers:
//       ph1: reads a0(8)+b0(4);  no stage          ; MFMA q00
//       ph2: reads b1(4);        no stage          ; MFMA q01
//       ph3: reads a1(8);  stage B(u+2) all [4 ld] ; MFMA q11
//       ph4: reg-only;     stage A(u+2) all [4 ld] ; MFMA q10
//     one counted s_waitcnt vmcnt(8) per tile (end of ph4): leaves tile
//     u+2's 8 loads in flight, guarantees tile u+1 (issued ph3/ph4 of tile
//     u-1, i.e. 4-5 phases earlier) landed. Every staging load thus gets
//     >=4 phases of latency cover (~900cy HBM miss).
//   - chunk swizzle: 16B chunk c of row r lives at slot c^(r&7); staging
//     keeps LDS linear (global source pre-swizzled per lane); ds_read_b128
//     frag reads are 2-way (free).
//   - XCD mapping: bm-banded / bn-fastest. Each XCD owns an 8-bm-tile A band
//     (4 MB, L2-resident); B panels are shared across XCDs and L3-hot.
// Workspace footprint: 152 MB (d_out doubles as the f32 residual buffer).

typedef __attribute__((ext_vector_type(8))) short s16x8;
typedef __attribute__((ext_vector_type(4))) short s16x4;
typedef __attribute__((ext_vector_type(4))) float f32x4;

__device__ __forceinline__ short f2bf(float x) {
  unsigned u = __builtin_bit_cast(unsigned, x);
  u = (u + 0x7FFFu + ((u >> 16) & 1u)) >> 16;
  return (short)u;
}
__device__ __forceinline__ float bf2f(short s) {
  unsigned u = ((unsigned)(unsigned short)s) << 16;
  return __builtin_bit_cast(float, u);
}

__device__ __forceinline__ void ld_g2l16(const short* g, short* l) {
  __builtin_amdgcn_global_load_lds(
      (const __attribute__((address_space(1))) void*)g,
      (__attribute__((address_space(3))) void*)l, 16, 0, 0);
}

// Fast GELU (tanh form via v_exp_f32; |err| ~1e-3 << bf16 noise).
__device__ __forceinline__ float fast_gelu(float v) {
  float y = 0.7978845608f * (v + 0.044715f * v * v * v);
  float ay = fabsf(y);
  float t = __expf(-2.0f * ay);
  float th = (1.0f - t) * __frcp_rn(1.0f + t);
  th = (y >= 0.f) ? th : -th;
  return 0.5f * v * (1.0f + th);
}

#define MFMA16(va, vb, vc) \
  __builtin_amdgcn_mfma_f32_16x16x32_bf16(va, vb, vc, 0, 0, 0)

// ---------------------------------------------------------------------------
// GEMM: C[M,N] = A[M,K] @ BT[N,K]^T  (A, BT bf16 row-major, K-contiguous).
// M is always 16384 (64 M-tiles, hardcoded). N,K multiples of 256.
// EPI: 0 = store bf16; 1 = store f32; 2 = +bias, fast GELU, store bf16;
//      4 = out += acc (+bias if non-null), f32 in-place accumulate.
// Launch: grid = 64*(N/256) blocks x 512 thr, dynamic LDS = 131072 B.
// ---------------------------------------------------------------------------
template <int EPI>
__global__ __launch_bounds__(512, 2) void gemm256(
    const short* __restrict__ A, const short* __restrict__ BT,
    void* __restrict__ outp, const float* __restrict__ bias, int N, int K) {
  extern __shared__ __align__(16) short smem[];

  const int t = threadIdx.x;
  const int lane = t & 63, w = t >> 6;
  const int wm = w >> 2, wn = w & 3;  // wave tile: rows wm*128, cols wn*64

  // bm-banded / bn-fastest XCD mapping. nwg = 64*nbn, 8 XCDs, so each XCD
  // gets seq = 0..8*nbn-1 -> bm band of 8 tiles (4 MB of A, L2-resident),
  // bn varies fastest (B panels shared across XCDs, L3-hot).
  const int nbn = N >> 8;
  const int oi = (int)blockIdx.x;
  const int seq = oi >> 3;
  const int bq = seq / nbn;
  const int bm = (oi & 7) * 8 + bq;
  const int bn = seq - bq * nbn;

  short* Ac = smem;           // A buffers: 2 x 16384 shorts (32 KB each)
  short* An = smem + 16384;
  short* Bc = smem + 32768;   // B buffers
  short* Bn = smem + 49152;

  // Staging: linear LDS slot s = q*512 + w*64 + lane covers
  // (row = h*128 + q*64 + w*8 + (lane>>3), slot = lane&3... chunk = lane&7);
  // the global chunk fetched into that slot is pre-swizzled:
  // c = (lane&7) ^ ((lane>>3)&7).
  const int l8 = lane >> 3;
  const int lcw = ((lane & 7) ^ l8) * 8;  // swizzled chunk offset (shorts)
  const short* gA = A + (size_t)(bm * 256 + w * 8 + l8) * K + lcw;
  const short* gB = BT + (size_t)(bn * 256 + w * 8 + l8) * K + lcw;
  const int lb = w * 512;  // wave's LDS base within a (half,q) block

  auto stage = [&](const short* g, short* buf, int h, int kt) {
    const size_t go = (size_t)(h * 128) * K + (size_t)kt * 64;
    ld_g2l16(g + go, buf + h * 8192 + lb);                          // q = 0
    ld_g2l16(g + go + (size_t)64 * K, buf + h * 8192 + 4096 + lb);  // q = 1
  };

  // Fragment reads: row r, chunk c=(ks*4+fc) at slot c^(r&7); r&7 == fr&7.
  const int fr = lane & 15, fc = lane >> 4;
  const int baseA = (wm * 128 + fr) * 64;
  const int baseB = (wn * 64 + fr) * 64;
  const int sl0 = (fc ^ (fr & 7)) * 8;
  const int sl1 = ((4 + fc) ^ (fr & 7)) * 8;

  f32x4 acc[8][4];
#pragma unroll
  for (int m = 0; m < 8; ++m)
#pragma unroll
    for (int n = 0; n < 4; ++n) acc[m][n] = (f32x4){0.f, 0.f, 0.f, 0.f};

  s16x8 a[4][2], b0[2][2], b1[2][2];

  const int nt = K >> 6;

  // Prologue: tile0 -> parity-0 bufs, tile1 -> parity-1 bufs (16 loads);
  // wait to 8 so tile0 is resident while tile1 stays in flight.
  stage(gA, Ac, 0, 0);
  stage(gA, Ac, 1, 0);
  stage(gB, Bc, 0, 0);
  stage(gB, Bc, 1, 0);
  if (nt > 1) {
    stage(gA, An, 0, 1);
    stage(gA, An, 1, 1);
    stage(gB, Bn, 0, 1);
    stage(gB, Bn, 1, 1);
    asm volatile("s_waitcnt vmcnt(8)" ::: "memory");  // tile0 landed
  } else {
    asm volatile("s_waitcnt vmcnt(0)" ::: "memory");
  }
  __builtin_amdgcn_s_barrier();
  asm volatile("" ::: "memory");

  for (int u = 0; u < nt; ++u) {
    const bool pf = (u + 2 < nt);  // tile u+2 goes into same-parity (cur) buf

    // ---- phase 1: read a0 (wave's A rows, low 64) + b0; MFMA q00
#pragma unroll
    for (int mi = 0; mi < 4; ++mi) {
      a[mi][0] = *(const s16x8*)(Ac + baseA + mi * 1024 + sl0);
      a[mi][1] = *(const s16x8*)(Ac + baseA + mi * 1024 + sl1);
    }
#pragma unroll
    for (int ni = 0; ni < 2; ++ni) {
      b0[ni][0] = *(const s16x8*)(Bc + baseB + ni * 1024 + sl0);
      b0[ni][1] = *(const s16x8*)(Bc + baseB + ni * 1024 + sl1);
    }
    __builtin_amdgcn_s_barrier();
    asm volatile("s_waitcnt lgkmcnt(0)" ::: "memory");
    __builtin_amdgcn_s_setprio(1);
#pragma unroll
    for (int mi = 0; mi < 4; ++mi)
#pragma unroll
      for (int ni = 0; ni < 2; ++ni) {
        acc[mi][ni] = MFMA16(a[mi][0], b0[ni][0], acc[mi][ni]);
        acc[mi][ni] = MFMA16(a[mi][1], b0[ni][1], acc[mi][ni]);
      }
    __builtin_amdgcn_s_setprio(0);
    __builtin_amdgcn_s_barrier();
    asm volatile("" ::: "memory");

    // ---- phase 2: read b1 (wave's B rows, high 32); MFMA q01
    //      (last read of the whole B region retires at this phase's end
    //       barrier -> B staging is legal from ph3 on)
#pragma unroll
    for (int ni = 0; ni < 2; ++ni) {
      b1[ni][0] = *(const s16x8*)(Bc + baseB + 2048 + ni * 1024 + sl0);
      b1[ni][1] = *(const s16x8*)(Bc + baseB + 2048 + ni * 1024 + sl1);
    }
    __builtin_amdgcn_s_barrier();
    asm volatile("s_waitcnt lgkmcnt(0)" ::: "memory");
    __builtin_amdgcn_s_setprio(1);
#pragma unroll
    for (int mi = 0; mi < 4; ++mi)
#pragma unroll
      for (int ni = 0; ni < 2; ++ni) {
        acc[mi][2 + ni] = MFMA16(a[mi][0], b1[ni][0], acc[mi][2 + ni]);
        acc[mi][2 + ni] = MFMA16(a[mi][1], b1[ni][1], acc[mi][2 + ni]);
      }
    __builtin_amdgcn_s_setprio(0);
    __builtin_amdgcn_s_barrier();
    asm volatile("" ::: "memory");

    // ---- phase 3: read a1 (wave's A rows, high 64); stage B(u+2) [4 ld];
    //      MFMA q11. (A region's last read retires at this phase's end
    //       barrier -> A staging is legal from ph4 on)
#pragma unroll
    for (int mi = 0; mi < 4; ++mi) {
      a[mi][0] = *(const s16x8*)(Ac + baseA + 4096 + mi * 1024 + sl0);
      a[mi][1] = *(const s16x8*)(Ac + baseA + 4096 + mi * 1024 + sl1);
    }
    if (pf) {
      stage(gB, Bc, 0, u + 2);
      stage(gB, Bc, 1, u + 2);
    }
    __builtin_amdgcn_s_barrier();
    asm volatile("s_waitcnt lgkmcnt(0)" ::: "memory");
    __builtin_amdgcn_s_setprio(1);
#pragma unroll
    for (int mi = 0; mi < 4; ++mi)
#pragma unroll
      for (int ni = 0; ni < 2; ++ni) {
        acc[4 + mi][2 + ni] = MFMA16(a[mi][0], b1[ni][0], acc[4 + mi][2 + ni]);
        acc[4 + mi][2 + ni] = MFMA16(a[mi][1], b1[ni][1], acc[4 + mi][2 + ni]);
      }
    __builtin_amdgcn_s_setprio(0);
    __builtin_amdgcn_s_barrier();
    asm volatile("" ::: "memory");

    // ---- phase 4: reg-only MFMA q10; stage A(u+2) [4 ld]; counted vmcnt
    if (pf) {
      stage(gA, Ac, 0, u + 2);
      stage(gA, Ac, 1, u + 2);
    }
    __builtin_amdgcn_s_setprio(1);
#pragma unroll
    for (int mi = 0; mi < 4; ++mi)
#pragma unroll
      for (int ni = 0; ni < 2; ++ni) {
        acc[4 + mi][ni] = MFMA16(a[mi][0], b0[ni][0], acc[4 + mi][ni]);
        acc[4 + mi][ni] = MFMA16(a[mi][1], b0[ni][1], acc[4 + mi][ni]);
      }
    __builtin_amdgcn_s_setprio(0);
    if (pf) {
      // leaves tile u+2's 8 loads in flight; tile u+1 is fully resident
      asm volatile("s_waitcnt vmcnt(8)" ::: "memory");
    } else {
      asm volatile("s_waitcnt vmcnt(0)" ::: "memory");  // tail drain
    }
    __builtin_amdgcn_s_barrier();
    asm volatile("" ::: "memory");

    short* tp = Ac; Ac = An; An = tp;
    tp = Bc; Bc = Bn; Bn = tp;
  }

  // Epilogue. 16x16 C/D layout: col = lane&15, row = (lane>>4)*4 + r.
  const int mb = bm * 256 + wm * 128;
  const int nb = bn * 256 + wn * 64;
  const int cr = (lane >> 4) * 4;
  const int cc = lane & 15;
#pragma unroll
  for (int m = 0; m < 8; ++m) {
#pragma unroll
    for (int n = 0; n < 4; ++n) {
#pragma unroll
      for (int r = 0; r < 4; ++r) {
        const size_t row = (size_t)(mb + m * 16 + cr + r);
        const size_t col = (size_t)(nb + n * 16 + cc);
        float v = acc[m][n][r];
        if constexpr (EPI == 0) {
          ((short*)outp)[row * N + col] = f2bf(v);
        } else if constexpr (EPI == 1) {
          ((float*)outp)[row * N + col] = v;
        } else if constexpr (EPI == 2) {
          v += bias[col];
          ((short*)outp)[row * N + col] = f2bf(fast_gelu(v));
        } else {  // EPI == 4
          float prev = ((float*)outp)[row * N + col];
          v += prev;
          if (bias) v += bias[col];
          ((float*)outp)[row * N + col] = v;
        }
      }
    }
  }
}

// ---------------------------------------------------------------------------
// Row LayerNorm over D=1024. Optional fp32 `add` (residual). Writes fp32
// and/or bf16. One block (256 thr) per row. Safe in-place (outf == in).
// ---------------------------------------------------------------------------
__global__ __launch_bounds__(256) void ln_k(
    const float* __restrict__ in, const float* __restrict__ add,
    const float* __restrict__ g, const float* __restrict__ b,
    float* __restrict__ outf, short* __restrict__ outb) {
  const int row = blockIdx.x;
  const size_t off = (size_t)row * 1024;
  const int t = threadIdx.x;
  float4 v = ((const float4*)(in + off))[t];
  if (add) {
    float4 w = ((const float4*)(add + off))[t];
    v.x += w.x; v.y += w.y; v.z += w.z; v.w += w.w;
  }
  float s = v.x + v.y + v.z + v.w;
  float ss = v.x * v.x + v.y * v.y + v.z * v.z + v.w * v.w;
#pragma unroll
  for (int o = 32; o > 0; o >>= 1) {
    s += __shfl_xor(s, o, 64);
    ss += __shfl_xor(ss, o, 64);
  }
  __shared__ float ps[4], pss[4];
  const int lane = t & 63, wave = t >> 6;
  if (lane == 0) { ps[wave] = s; pss[wave] = ss; }
  __syncthreads();
  s = ps[0] + ps[1] + ps[2] + ps[3];
  ss = pss[0] + pss[1] + pss[2] + pss[3];
  const float mean = s * (1.0f / 1024.0f);
  const float var = ss * (1.0f / 1024.0f) - mean * mean;
  const float rstd = rsqrtf(var + 1e-6f);
  const float4 gv = ((const float4*)g)[t];
  const float4 bv = ((const float4*)b)[t];
  float4 o4;
  o4.x = (v.x - mean) * rstd * gv.x + bv.x;
  o4.y = (v.y - mean) * rstd * gv.y + bv.y;
  o4.z = (v.z - mean) * rstd * gv.z + bv.z;
  o4.w = (v.w - mean) * rstd * gv.w + bv.w;
  if (outf) ((float4*)(outf + off))[t] = o4;
  if (outb) {
    s16x4 ob;
    ob[0] = f2bf(o4.x); ob[1] = f2bf(o4.y);
    ob[2] = f2bf(o4.z); ob[3] = f2bf(o4.w);
    *(s16x4*)(outb + off + t * 4) = ob;
  }
}

// ---------------------------------------------------------------------------
// Weight convert+transpose: W[K,N] fp32 -> WT[N,K] bf16. 32x32 tiles.
// ---------------------------------------------------------------------------
__global__ __launch_bounds__(256) void wconv_t(const float* __restrict__ W,
                                               short* __restrict__ WT, int K,
                                               int N) {
  __shared__ float tile[32][33];
  const int t = threadIdx.x;
  const int c = t & 31, r = t >> 5;
  const int n0 = blockIdx.x * 32, k0 = blockIdx.y * 32;
#pragma unroll
  for (int rr = r; rr < 32; rr += 8)
    tile[rr][c] = W[(size_t)(k0 + rr) * N + n0 + c];
  __syncthreads();
#pragma unroll
  for (int rr = r; rr < 32; rr += 8)
    WT[(size_t)(n0 + rr) * K + k0 + c] = f2bf(tile[c][rr]);
}

// ---------------------------------------------------------------------------
// Per-token head-mixing attention + faithful-reshape scramble.
// ---------------------------------------------------------------------------
__global__ __launch_bounds__(256) void attn_k(const short* __restrict__ qkv,
                                              short* __restrict__ omix) {
  __shared__ float Qs[4][16][64];
  __shared__ float Ks[4][16][64];
  __shared__ float Vs[4][16][64];
  __shared__ float Ps[4][16][16];
  const int lane = threadIdx.x & 63;
  const int wave = threadIdx.x >> 6;
  const int tok = blockIdx.x * 4 + wave;
  const short* base = qkv + (size_t)tok * 3072;

#pragma unroll
  for (int half = 0; half < 2; half++) {
    const int e = half * 512 + lane * 8;
    const int h = e >> 6, d = e & 63;
    s16x8 rq = *(const s16x8*)(base + e);
    s16x8 rk = *(const s16x8*)(base + 1024 + e);
    s16x8 rv = *(const s16x8*)(base + 2048 + e);
#pragma unroll
    for (int j = 0; j < 8; j++) {
      Qs[wave][h][d + j] = bf2f(rq[j]);
      Ks[wave][h][d + j] = bf2f(rk[j]);
      Vs[wave][h][d + j] = bf2f(rv[j]);
    }
  }
  __syncthreads();

  const int h = lane & 15;
  const int g0 = (lane >> 4) * 4;
  float sc[4] = {0.f, 0.f, 0.f, 0.f};
  for (int d = 0; d < 64; d++) {
    const float qv = Qs[wave][h][d];
#pragma unroll
    for (int i = 0; i < 4; i++) sc[i] += qv * Ks[wave][g0 + i][d];
  }
#pragma unroll
  for (int i = 0; i < 4; i++) sc[i] *= 0.125f;
  float m = fmaxf(fmaxf(sc[0], sc[1]), fmaxf(sc[2], sc[3]));
  m = fmaxf(m, __shfl_xor(m, 16, 64));
  m = fmaxf(m, __shfl_xor(m, 32, 64));
  float e[4], sum = 0.f;
#pragma unroll
  for (int i = 0; i < 4; i++) { e[i] = __expf(sc[i] - m); sum += e[i]; }
  sum += __shfl_xor(sum, 16, 64);
  sum += __shfl_xor(sum, 32, 64);
  const float inv = __frcp_rn(sum);
#pragma unroll
  for (int i = 0; i < 4; i++) Ps[wave][h][g0 + i] = e[i] * inv;
  __syncthreads();

  const int d0 = (lane >> 4) * 16;
  float o[16];
#pragma unroll
  for (int dd = 0; dd < 16; dd++) o[dd] = 0.f;
  for (int gg = 0; gg < 16; gg++) {
    const float pv = Ps[wave][h][gg];
#pragma unroll
    for (int dd = 0; dd < 16; dd++) o[dd] += pv * Vs[wave][gg][d0 + dd];
  }

  const int b = tok >> 12, t = tok & 4095;
  const size_t dst =
      ((size_t)(b * 4096 + h * 256 + (t >> 4))) * 1024 + (t & 15) * 64 + d0;
  s16x8 w0, w1;
#pragma unroll
  for (int j = 0; j < 8; j++) { w0[j] = f2bf(o[j]); w1[j] = f2bf(o[8 + j]); }
  *(s16x8*)(omix + dst) = w0;
  *(s16x8*)(omix + dst + 8) = w1;
}

// ---------------------------------------------------------------------------
extern "C" void kernel_launch(void* const* d_in, const int* in_sizes, int n_in,
                              void* d_out, int out_size, void* d_ws,
                              size_t ws_size, hipStream_t stream) {
  const float* x    = (const float*)d_in[0];
  const float* wq   = (const float*)d_in[1];
  const float* wk   = (const float*)d_in[2];
  const float* wv   = (const float*)d_in[3];
  const float* wo   = (const float*)d_in[4];
  const float* ln1g = (const float*)d_in[5];
  const float* ln1b = (const float*)d_in[6];
  const float* w1   = (const float*)d_in[7];
  const float* b1   = (const float*)d_in[8];
  const float* w2   = (const float*)d_in[9];
  const float* b2   = (const float*)d_in[10];
  const float* ln2g = (const float*)d_in[11];
  const float* ln2b = (const float*)d_in[12];
  float* out = (float*)d_out;  // [16384,1024] f32; doubles as o2/q2 buffer

  char* ws = (char*)d_ws;
  const size_t MB = 1024ull * 1024ull;
  const size_t NEEDED = 152 * MB;
  if (ws_size < NEEDED) return;  // fail-numeric instead of page-fault

  short* QKV  = (short*)(ws + 0);        // phase1 [16384,3072] bf16
  short* Q2B  = (short*)(ws + 0);        // phase2 [16384,1024] bf16
  short* Hbuf = (short*)(ws + 32 * MB);  // phase2 [16384,2048] bf16
  short* X1 = (short*)(ws + 96 * MB);    // x1, then o_mixed bf16
  short* WQKVT = (short*)(ws + 128 * MB);
  short* WOT   = (short*)(ws + 134 * MB);
  short* W1T   = (short*)(ws + 136 * MB);
  short* W2aT  = (short*)(ws + 144 * MB);
  short* W2bT  = (short*)(ws + 148 * MB);

  const dim3 B256(256);
  const dim3 B512(512);
  const unsigned LDS = 131072;  // 128 KiB dynamic LDS for gemm256

  static bool attr_done = false;
  if (!attr_done) {
    attr_done = true;
    void (*k0)(const short*, const short*, void*, const float*, int, int) =
        gemm256<0>;
    void (*k1)(const short*, const short*, void*, const float*, int, int) =
        gemm256<1>;
    void (*k2)(const short*, const short*, void*, const float*, int, int) =
        gemm256<2>;
    void (*k4)(const short*, const short*, void*, const float*, int, int) =
        gemm256<4>;
    (void)hipFuncSetAttribute((const void*)k0,
        hipFuncAttributeMaxDynamicSharedMemorySize, (int)LDS);
    (void)hipFuncSetAttribute((const void*)k1,
        hipFuncAttributeMaxDynamicSharedMemorySize, (int)LDS);
    (void)hipFuncSetAttribute((const void*)k2,
        hipFuncAttributeMaxDynamicSharedMemorySize, (int)LDS);
    (void)hipFuncSetAttribute((const void*)k4,
        hipFuncAttributeMaxDynamicSharedMemorySize, (int)LDS);
  }

  wconv_t<<<dim3(32, 32), B256, 0, stream>>>(wq, WQKVT, 1024, 1024);
  wconv_t<<<dim3(32, 32), B256, 0, stream>>>(wk, WQKVT + 1024 * 1024, 1024, 1024);
  wconv_t<<<dim3(32, 32), B256, 0, stream>>>(wv, WQKVT + 2048 * 1024, 1024, 1024);
  wconv_t<<<dim3(32, 32), B256, 0, stream>>>(wo, WOT, 1024, 1024);
  wconv_t<<<dim3(128, 32), B256, 0, stream>>>(w1, W1T, 1024, 4096);
  wconv_t<<<dim3(32, 64), B256, 0, stream>>>(w2, W2aT, 2048, 1024);
  wconv_t<<<dim3(32, 64), B256, 0, stream>>>(w2 + 2048 * 1024, W2bT, 2048, 1024);

  // x1 = LN1(x) -> bf16
  ln_k<<<16384, B256, 0, stream>>>(x, nullptr, ln1g, ln1b, nullptr, X1);

  // QKV = x1 @ [wq|wk|wv]   (grid 64 x 12 = 768 blocks)
  gemm256<0><<<dim3(768), B512, LDS, stream>>>(X1, WQKVT, QKV, nullptr,
                                               3072, 1024);

  // attention + scramble -> o_mixed (reuses X1 region)
  attn_k<<<4096, B256, 0, stream>>>(QKV, X1);

  // o2 = o_mixed @ wo -> f32 into d_out   (64 x 4 = 256 blocks)
  gemm256<1><<<dim3(256), B512, LDS, stream>>>(X1, WOT, out, nullptr,
                                               1024, 1024);

  // q2 = LN1(o2 + x): f32 in-place in d_out, bf16 copy in Q2B
  ln_k<<<16384, B256, 0, stream>>>(out, x, ln1g, ln1b, out, Q2B);

  // FFN half A  (W1: 64 x 8 = 512 blocks; W2: 256 blocks)
  gemm256<2><<<dim3(512), B512, LDS, stream>>>(Q2B, W1T, Hbuf, b1,
                                               2048, 1024);
  gemm256<4><<<dim3(256), B512, LDS, stream>>>(Hbuf, W2aT, out, nullptr,
                                               1024, 2048);

  // FFN half B
  gemm256<2><<<dim3(512), B512, LDS, stream>>>(Q2B, W1T + 2048 * 1024, Hbuf,
                                               b1 + 2048, 2048, 1024);
  gemm256<4><<<dim3(256), B512, LDS, stream>>>(Hbuf, W2bT, out, b2,
                                               1024, 2048);

  // out = LN2(y) in-place
  ln_k<<<16384, B256, 0, stream>>>(out, nullptr, ln2g, ln2b, out, nullptr);
}

// Round 4
// 811.982 us; speedup vs baseline: 1.1103x; 1.0203x over previous
//
#include <hip/hip_runtime.h>

// Encoder block: LN1 -> QKV -> per-token head-mix attention -> scramble ->
// WO -> +x,LN1 -> W1+GELU (2 halves) -> W2 accum (+b2,+q2) -> LN2 in-place.
//
// GEMM: 256x256 8-wave pipelined schedule, revision 4:
//   identical phase/barrier/vmcnt schedule to rev 3 (race-free, verified),
//   but LDS access is now addrspace(3)-explicit with parity-offset buffers
//   (no pointer-swap PHIs) to guarantee ds_read_b128 codegen for fragment
//   reads (flat_load fallback suspected of the rev-3 ~3x K-loop slowdown).
//   - tile 256x256, BK=64, 512 thr = 8 waves (2M x 4N), wave tile 128x64.
//   - LDS 128 KiB dynamic: A,B double-buffered by tile parity (u&1).
//   - Phases per K-tile (halves h0/h1 are ROW ranges 0-127/128-255; last
//     B-region read retires at ph2-end barrier, last A-region read at
//     ph3-end barrier -> staging tile u+2 into the current-parity buffer
//     is legal from ph3 (B) / ph4 (A)):
//       ph1: reads a0(8)+b0(4);  no stage          ; MFMA q00
//       ph2: reads b1(4);        no stage          ; MFMA q01
//       ph3: reads a1(8);  stage B(u+2) all [4 ld] ; MFMA q11
//       ph4: reg-only;     stage A(u+2) all [4 ld] ; MFMA q10
//     one counted s_waitcnt vmcnt(8) per tile (end of ph4): tile u+1's 8
//     loads (issued 4-5 phases earlier) have landed; tile u+2's 8 stay in
//     flight (~900cy HBM latency covered).
//   - chunk swizzle: 16B chunk c of row r lives at slot c^(r&7); staging
//     keeps LDS linear (global source pre-swizzled per lane); ds_read_b128
//     frag reads are 2-way (free).
//   - XCD mapping: bm-banded / bn-fastest (FETCH 135->49 MB measured).
// Workspace footprint: 152 MB (d_out doubles as the f32 residual buffer).

typedef __attribute__((ext_vector_type(8))) short s16x8;
typedef __attribute__((ext_vector_type(4))) short s16x4;
typedef __attribute__((ext_vector_type(4))) float f32x4;

__device__ __forceinline__ short f2bf(float x) {
  unsigned u = __builtin_bit_cast(unsigned, x);
  u = (u + 0x7FFFu + ((u >> 16) & 1u)) >> 16;
  return (short)u;
}
__device__ __forceinline__ float bf2f(short s) {
  unsigned u = ((unsigned)(unsigned short)s) << 16;
  return __builtin_bit_cast(float, u);
}

__device__ __forceinline__ void ld_g2l16(const short* g, const short* l) {
  __builtin_amdgcn_global_load_lds(
      (const __attribute__((address_space(1))) void*)g,
      (__attribute__((address_space(3))) void*)l, 16, 0, 0);
}

// Guaranteed-DS vector read: explicit addrspace(3) so codegen emits
// ds_read_b128 (never flat_load).
__device__ __forceinline__ s16x8 lds_read8(const short* smem, int off) {
  const __attribute__((address_space(3))) short* p =
      (const __attribute__((address_space(3))) short*)smem;
  return *(const __attribute__((address_space(3))) s16x8*)(p + off);
}

// Fast GELU (tanh form via v_exp_f32; |err| ~1e-3 << bf16 noise).
__device__ __forceinline__ float fast_gelu(float v) {
  float y = 0.7978845608f * (v + 0.044715f * v * v * v);
  float ay = fabsf(y);
  float t = __expf(-2.0f * ay);
  float th = (1.0f - t) * __frcp_rn(1.0f + t);
  th = (y >= 0.f) ? th : -th;
  return 0.5f * v * (1.0f + th);
}

#define MFMA16(va, vb, vc) \
  __builtin_amdgcn_mfma_f32_16x16x32_bf16(va, vb, vc, 0, 0, 0)

// ---------------------------------------------------------------------------
// GEMM: C[M,N] = A[M,K] @ BT[N,K]^T  (A, BT bf16 row-major, K-contiguous).
// M is always 16384 (64 M-tiles, hardcoded). N,K multiples of 256.
// EPI: 0 = store bf16; 1 = store f32; 2 = +bias, fast GELU, store bf16;
//      4 = out += acc (+bias if non-null), f32 in-place accumulate.
// Launch: grid = 64*(N/256) blocks x 512 thr, dynamic LDS = 131072 B.
// ---------------------------------------------------------------------------
template <int EPI>
__global__ __launch_bounds__(512, 2) void gemm256(
    const short* __restrict__ A, const short* __restrict__ BT,
    void* __restrict__ outp, const float* __restrict__ bias, int N, int K) {
  extern __shared__ __align__(16) short smem[];

  const int t = threadIdx.x;
  const int lane = t & 63, w = t >> 6;
  const int wm = w >> 2, wn = w & 3;  // wave tile: rows wm*128, cols wn*64

  // bm-banded / bn-fastest XCD mapping. nwg = 64*nbn, 8 XCDs, so each XCD
  // gets seq = 0..8*nbn-1 -> bm band of 8 tiles (4 MB of A, L2-resident),
  // bn varies fastest (B panels shared across XCDs, L3-hot).
  const int nbn = N >> 8;
  const int oi = (int)blockIdx.x;
  const int seq = oi >> 3;
  const int bq = seq / nbn;
  const int bm = (oi & 7) * 8 + bq;
  const int bn = seq - bq * nbn;

  // LDS map (shorts): A parity-0 at 0, A parity-1 at 16384,
  //                   B parity-0 at 32768, B parity-1 at 49152.

  // Staging: linear LDS slot s = q*512 + w*64 + lane covers
  // (row = h*128 + q*64 + w*8 + (lane>>3), chunk slot = lane&7); the global
  // chunk fetched into that slot is pre-swizzled: c = (lane&7)^((lane>>3)&7).
  const int l8 = lane >> 3;
  const int lcw = ((lane & 7) ^ l8) * 8;  // swizzled chunk offset (shorts)
  const short* gA = A + (size_t)(bm * 256 + w * 8 + l8) * K + lcw;
  const short* gB = BT + (size_t)(bn * 256 + w * 8 + l8) * K + lcw;
  const int lb = w * 512;  // wave's LDS base within a (half,q) block

  auto stage = [&](const short* g, int bufo, int h, int kt) {
    const int go = h * 128 * K + kt * 64;  // fits int: <128*3072+64*64
    ld_g2l16(g + go, smem + bufo + h * 8192 + lb);                // q = 0
    ld_g2l16(g + go + 64 * K, smem + bufo + h * 8192 + 4096 + lb);  // q = 1
  };

  // Fragment reads: row r, chunk c=(ks*4+fc) at slot c^(r&7); r&7 == fr&7.
  const int fr = lane & 15, fc = lane >> 4;
  const int baseA = (wm * 128 + fr) * 64;
  const int baseB = (wn * 64 + fr) * 64;
  const int sl0 = (fc ^ (fr & 7)) * 8;
  const int sl1 = ((4 + fc) ^ (fr & 7)) * 8;

  f32x4 acc[8][4];
#pragma unroll
  for (int m = 0; m < 8; ++m)
#pragma unroll
    for (int n = 0; n < 4; ++n) acc[m][n] = (f32x4){0.f, 0.f, 0.f, 0.f};

  s16x8 a[4][2], b0[2][2], b1[2][2];

  const int nt = K >> 6;

  // Prologue: tile0 -> parity-0 bufs, tile1 -> parity-1 bufs (16 loads);
  // wait to 8 so tile0 is resident while tile1 stays in flight.
  stage(gA, 0, 0, 0);
  stage(gA, 0, 1, 0);
  stage(gB, 32768, 0, 0);
  stage(gB, 32768, 1, 0);
  if (nt > 1) {
    stage(gA, 16384, 0, 1);
    stage(gA, 16384, 1, 1);
    stage(gB, 49152, 0, 1);
    stage(gB, 49152, 1, 1);
    asm volatile("s_waitcnt vmcnt(8)" ::: "memory");  // tile0 landed
  } else {
    asm volatile("s_waitcnt vmcnt(0)" ::: "memory");
  }
  __builtin_amdgcn_s_barrier();
  asm volatile("" ::: "memory");

  for (int u = 0; u < nt; ++u) {
    const bool pf = (u + 2 < nt);  // tile u+2 goes into same-parity (cur) buf
    const int pa = (u & 1) << 14;  // current A buffer offset (shorts)
    const int pb = 32768 + pa;     // current B buffer offset

    // ---- phase 1: read a0 (wave's A rows, low 64) + b0; MFMA q00
#pragma unroll
    for (int mi = 0; mi < 4; ++mi) {
      a[mi][0] = lds_read8(smem, pa + baseA + mi * 1024 + sl0);
      a[mi][1] = lds_read8(smem, pa + baseA + mi * 1024 + sl1);
    }
#pragma unroll
    for (int ni = 0; ni < 2; ++ni) {
      b0[ni][0] = lds_read8(smem, pb + baseB + ni * 1024 + sl0);
      b0[ni][1] = lds_read8(smem, pb + baseB + ni * 1024 + sl1);
    }
    __builtin_amdgcn_s_barrier();
    asm volatile("s_waitcnt lgkmcnt(0)" ::: "memory");
    __builtin_amdgcn_s_setprio(1);
#pragma unroll
    for (int mi = 0; mi < 4; ++mi)
#pragma unroll
      for (int ni = 0; ni < 2; ++ni) {
        acc[mi][ni] = MFMA16(a[mi][0], b0[ni][0], acc[mi][ni]);
        acc[mi][ni] = MFMA16(a[mi][1], b0[ni][1], acc[mi][ni]);
      }
    __builtin_amdgcn_s_setprio(0);
    __builtin_amdgcn_s_barrier();
    asm volatile("" ::: "memory");

    // ---- phase 2: read b1 (wave's B rows, high 32); MFMA q01
    //      (last read of the whole B region retires at this phase's end
    //       barrier -> B staging is legal from ph3 on)
#pragma unroll
    for (int ni = 0; ni < 2; ++ni) {
      b1[ni][0] = lds_read8(smem, pb + baseB + 2048 + ni * 1024 + sl0);
      b1[ni][1] = lds_read8(smem, pb + baseB + 2048 + ni * 1024 + sl1);
    }
    __builtin_amdgcn_s_barrier();
    asm volatile("s_waitcnt lgkmcnt(0)" ::: "memory");
    __builtin_amdgcn_s_setprio(1);
#pragma unroll
    for (int mi = 0; mi < 4; ++mi)
#pragma unroll
      for (int ni = 0; ni < 2; ++ni) {
        acc[mi][2 + ni] = MFMA16(a[mi][0], b1[ni][0], acc[mi][2 + ni]);
        acc[mi][2 + ni] = MFMA16(a[mi][1], b1[ni][1], acc[mi][2 + ni]);
      }
    __builtin_amdgcn_s_setprio(0);
    __builtin_amdgcn_s_barrier();
    asm volatile("" ::: "memory");

    // ---- phase 3: read a1 (wave's A rows, high 64); stage B(u+2) [4 ld];
    //      MFMA q11. (A region's last read retires at this phase's end
    //       barrier -> A staging is legal from ph4 on)
#pragma unroll
    for (int mi = 0; mi < 4; ++mi) {
      a[mi][0] = lds_read8(smem, pa + baseA + 4096 + mi * 1024 + sl0);
      a[mi][1] = lds_read8(smem, pa + baseA + 4096 + mi * 1024 + sl1);
    }
    if (pf) {
      stage(gB, pb, 0, u + 2);
      stage(gB, pb, 1, u + 2);
    }
    __builtin_amdgcn_s_barrier();
    asm volatile("s_waitcnt lgkmcnt(0)" ::: "memory");
    __builtin_amdgcn_s_setprio(1);
#pragma unroll
    for (int mi = 0; mi < 4; ++mi)
#pragma unroll
      for (int ni = 0; ni < 2; ++ni) {
        acc[4 + mi][2 + ni] = MFMA16(a[mi][0], b1[ni][0], acc[4 + mi][2 + ni]);
        acc[4 + mi][2 + ni] = MFMA16(a[mi][1], b1[ni][1], acc[4 + mi][2 + ni]);
      }
    __builtin_amdgcn_s_setprio(0);
    __builtin_amdgcn_s_barrier();
    asm volatile("" ::: "memory");

    // ---- phase 4: reg-only MFMA q10; stage A(u+2) [4 ld]; counted vmcnt
    if (pf) {
      stage(gA, pa, 0, u + 2);
      stage(gA, pa, 1, u + 2);
    }
    __builtin_amdgcn_s_setprio(1);
#pragma unroll
    for (int mi = 0; mi < 4; ++mi)
#pragma unroll
      for (int ni = 0; ni < 2; ++ni) {
        acc[4 + mi][ni] = MFMA16(a[mi][0], b0[ni][0], acc[4 + mi][ni]);
        acc[4 + mi][ni] = MFMA16(a[mi][1], b0[ni][1], acc[4 + mi][ni]);
      }
    __builtin_amdgcn_s_setprio(0);
    if (pf) {
      // leaves tile u+2's 8 loads in flight; tile u+1 is fully resident
      asm volatile("s_waitcnt vmcnt(8)" ::: "memory");
    } else {
      asm volatile("s_waitcnt vmcnt(0)" ::: "memory");  // tail drain
    }
    __builtin_amdgcn_s_barrier();
    asm volatile("" ::: "memory");
  }

  // Epilogue. 16x16 C/D layout: col = lane&15, row = (lane>>4)*4 + r.
  const int mb = bm * 256 + wm * 128;
  const int nb = bn * 256 + wn * 64;
  const int cr = (lane >> 4) * 4;
  const int cc = lane & 15;
#pragma unroll
  for (int m = 0; m < 8; ++m) {
#pragma unroll
    for (int n = 0; n < 4; ++n) {
#pragma unroll
      for (int r = 0; r < 4; ++r) {
        const size_t row = (size_t)(mb + m * 16 + cr + r);
        const size_t col = (size_t)(nb + n * 16 + cc);
        float v = acc[m][n][r];
        if constexpr (EPI == 0) {
          ((short*)outp)[row * N + col] = f2bf(v);
        } else if constexpr (EPI == 1) {
          ((float*)outp)[row * N + col] = v;
        } else if constexpr (EPI == 2) {
          v += bias[col];
          ((short*)outp)[row * N + col] = f2bf(fast_gelu(v));
        } else {  // EPI == 4
          float prev = ((float*)outp)[row * N + col];
          v += prev;
          if (bias) v += bias[col];
          ((float*)outp)[row * N + col] = v;
        }
      }
    }
  }
}

// ---------------------------------------------------------------------------
// Row LayerNorm over D=1024. Optional fp32 `add` (residual). Writes fp32
// and/or bf16. One block (256 thr) per row. Safe in-place (outf == in).
// ---------------------------------------------------------------------------
__global__ __launch_bounds__(256) void ln_k(
    const float* __restrict__ in, const float* __restrict__ add,
    const float* __restrict__ g, const float* __restrict__ b,
    float* __restrict__ outf, short* __restrict__ outb) {
  const int row = blockIdx.x;
  const size_t off = (size_t)row * 1024;
  const int t = threadIdx.x;
  float4 v = ((const float4*)(in + off))[t];
  if (add) {
    float4 w = ((const float4*)(add + off))[t];
    v.x += w.x; v.y += w.y; v.z += w.z; v.w += w.w;
  }
  float s = v.x + v.y + v.z + v.w;
  float ss = v.x * v.x + v.y * v.y + v.z * v.z + v.w * v.w;
#pragma unroll
  for (int o = 32; o > 0; o >>= 1) {
    s += __shfl_xor(s, o, 64);
    ss += __shfl_xor(ss, o, 64);
  }
  __shared__ float ps[4], pss[4];
  const int lane = t & 63, wave = t >> 6;
  if (lane == 0) { ps[wave] = s; pss[wave] = ss; }
  __syncthreads();
  s = ps[0] + ps[1] + ps[2] + ps[3];
  ss = pss[0] + pss[1] + pss[2] + pss[3];
  const float mean = s * (1.0f / 1024.0f);
  const float var = ss * (1.0f / 1024.0f) - mean * mean;
  const float rstd = rsqrtf(var + 1e-6f);
  const float4 gv = ((const float4*)g)[t];
  const float4 bv = ((const float4*)b)[t];
  float4 o4;
  o4.x = (v.x - mean) * rstd * gv.x + bv.x;
  o4.y = (v.y - mean) * rstd * gv.y + bv.y;
  o4.z = (v.z - mean) * rstd * gv.z + bv.z;
  o4.w = (v.w - mean) * rstd * gv.w + bv.w;
  if (outf) ((float4*)(outf + off))[t] = o4;
  if (outb) {
    s16x4 ob;
    ob[0] = f2bf(o4.x); ob[1] = f2bf(o4.y);
    ob[2] = f2bf(o4.z); ob[3] = f2bf(o4.w);
    *(s16x4*)(outb + off + t * 4) = ob;
  }
}

// ---------------------------------------------------------------------------
// Weight convert+transpose: W[K,N] fp32 -> WT[N,K] bf16. 32x32 tiles.
// ---------------------------------------------------------------------------
__global__ __launch_bounds__(256) void wconv_t(const float* __restrict__ W,
                                               short* __restrict__ WT, int K,
                                               int N) {
  __shared__ float tile[32][33];
  const int t = threadIdx.x;
  const int c = t & 31, r = t >> 5;
  const int n0 = blockIdx.x * 32, k0 = blockIdx.y * 32;
#pragma unroll
  for (int rr = r; rr < 32; rr += 8)
    tile[rr][c] = W[(size_t)(k0 + rr) * N + n0 + c];
  __syncthreads();
#pragma unroll
  for (int rr = r; rr < 32; rr += 8)
    WT[(size_t)(n0 + rr) * K + k0 + c] = f2bf(tile[c][rr]);
}

// ---------------------------------------------------------------------------
// Per-token head-mixing attention + faithful-reshape scramble.
// ---------------------------------------------------------------------------
__global__ __launch_bounds__(256) void attn_k(const short* __restrict__ qkv,
                                              short* __restrict__ omix) {
  __shared__ float Qs[4][16][64];
  __shared__ float Ks[4][16][64];
  __shared__ float Vs[4][16][64];
  __shared__ float Ps[4][16][16];
  const int lane = threadIdx.x & 63;
  const int wave = threadIdx.x >> 6;
  const int tok = blockIdx.x * 4 + wave;
  const short* base = qkv + (size_t)tok * 3072;

#pragma unroll
  for (int half = 0; half < 2; half++) {
    const int e = half * 512 + lane * 8;
    const int h = e >> 6, d = e & 63;
    s16x8 rq = *(const s16x8*)(base + e);
    s16x8 rk = *(const s16x8*)(base + 1024 + e);
    s16x8 rv = *(const s16x8*)(base + 2048 + e);
#pragma unroll
    for (int j = 0; j < 8; j++) {
      Qs[wave][h][d + j] = bf2f(rq[j]);
      Ks[wave][h][d + j] = bf2f(rk[j]);
      Vs[wave][h][d + j] = bf2f(rv[j]);
    }
  }
  __syncthreads();

  const int h = lane & 15;
  const int g0 = (lane >> 4) * 4;
  float sc[4] = {0.f, 0.f, 0.f, 0.f};
  for (int d = 0; d < 64; d++) {
    const float qv = Qs[wave][h][d];
#pragma unroll
    for (int i = 0; i < 4; i++) sc[i] += qv * Ks[wave][g0 + i][d];
  }
#pragma unroll
  for (int i = 0; i < 4; i++) sc[i] *= 0.125f;
  float m = fmaxf(fmaxf(sc[0], sc[1]), fmaxf(sc[2], sc[3]));
  m = fmaxf(m, __shfl_xor(m, 16, 64));
  m = fmaxf(m, __shfl_xor(m, 32, 64));
  float e[4], sum = 0.f;
#pragma unroll
  for (int i = 0; i < 4; i++) { e[i] = __expf(sc[i] - m); sum += e[i]; }
  sum += __shfl_xor(sum, 16, 64);
  sum += __shfl_xor(sum, 32, 64);
  const float inv = __frcp_rn(sum);
#pragma unroll
  for (int i = 0; i < 4; i++) Ps[wave][h][g0 + i] = e[i] * inv;
  __syncthreads();

  const int d0 = (lane >> 4) * 16;
  float o[16];
#pragma unroll
  for (int dd = 0; dd < 16; dd++) o[dd] = 0.f;
  for (int gg = 0; gg < 16; gg++) {
    const float pv = Ps[wave][h][gg];
#pragma unroll
    for (int dd = 0; dd < 16; dd++) o[dd] += pv * Vs[wave][gg][d0 + dd];
  }

  const int b = tok >> 12, t = tok & 4095;
  const size_t dst =
      ((size_t)(b * 4096 + h * 256 + (t >> 4))) * 1024 + (t & 15) * 64 + d0;
  s16x8 w0, w1;
#pragma unroll
  for (int j = 0; j < 8; j++) { w0[j] = f2bf(o[j]); w1[j] = f2bf(o[8 + j]); }
  *(s16x8*)(omix + dst) = w0;
  *(s16x8*)(omix + dst + 8) = w1;
}

// ---------------------------------------------------------------------------
extern "C" void kernel_launch(void* const* d_in, const int* in_sizes, int n_in,
                              void* d_out, int out_size, void* d_ws,
                              size_t ws_size, hipStream_t stream) {
  const float* x    = (const float*)d_in[0];
  const float* wq   = (const float*)d_in[1];
  const float* wk   = (const float*)d_in[2];
  const float* wv   = (const float*)d_in[3];
  const float* wo   = (const float*)d_in[4];
  const float* ln1g = (const float*)d_in[5];
  const float* ln1b = (const float*)d_in[6];
  const float* w1   = (const float*)d_in[7];
  const float* b1   = (const float*)d_in[8];
  const float* w2   = (const float*)d_in[9];
  const float* b2   = (const float*)d_in[10];
  const float* ln2g = (const float*)d_in[11];
  const float* ln2b = (const float*)d_in[12];
  float* out = (float*)d_out;  // [16384,1024] f32; doubles as o2/q2 buffer

  char* ws = (char*)d_ws;
  const size_t MB = 1024ull * 1024ull;
  const size_t NEEDED = 152 * MB;
  if (ws_size < NEEDED) return;  // fail-numeric instead of page-fault

  short* QKV  = (short*)(ws + 0);        // phase1 [16384,3072] bf16
  short* Q2B  = (short*)(ws + 0);        // phase2 [16384,1024] bf16
  short* Hbuf = (short*)(ws + 32 * MB);  // phase2 [16384,2048] bf16
  short* X1 = (short*)(ws + 96 * MB);    // x1, then o_mixed bf16
  short* WQKVT = (short*)(ws + 128 * MB);
  short* WOT   = (short*)(ws + 134 * MB);
  short* W1T   = (short*)(ws + 136 * MB);
  short* W2aT  = (short*)(ws + 144 * MB);
  short* W2bT  = (short*)(ws + 148 * MB);

  const dim3 B256(256);
  const dim3 B512(512);
  const unsigned LDS = 131072;  // 128 KiB dynamic LDS for gemm256

  static bool attr_done = false;
  if (!attr_done) {
    attr_done = true;
    void (*k0)(const short*, const short*, void*, const float*, int, int) =
        gemm256<0>;
    void (*k1)(const short*, const short*, void*, const float*, int, int) =
        gemm256<1>;
    void (*k2)(const short*, const short*, void*, const float*, int, int) =
        gemm256<2>;
    void (*k4)(const short*, const short*, void*, const float*, int, int) =
        gemm256<4>;
    (void)hipFuncSetAttribute((const void*)k0,
        hipFuncAttributeMaxDynamicSharedMemorySize, (int)LDS);
    (void)hipFuncSetAttribute((const void*)k1,
        hipFuncAttributeMaxDynamicSharedMemorySize, (int)LDS);
    (void)hipFuncSetAttribute((const void*)k2,
        hipFuncAttributeMaxDynamicSharedMemorySize, (int)LDS);
    (void)hipFuncSetAttribute((const void*)k4,
        hipFuncAttributeMaxDynamicSharedMemorySize, (int)LDS);
  }

  wconv_t<<<dim3(32, 32), B256, 0, stream>>>(wq, WQKVT, 1024, 1024);
  wconv_t<<<dim3(32, 32), B256, 0, stream>>>(wk, WQKVT + 1024 * 1024, 1024, 1024);
  wconv_t<<<dim3(32, 32), B256, 0, stream>>>(wv, WQKVT + 2048 * 1024, 1024, 1024);
  wconv_t<<<dim3(32, 32), B256, 0, stream>>>(wo, WOT, 1024, 1024);
  wconv_t<<<dim3(128, 32), B256, 0, stream>>>(w1, W1T, 1024, 4096);
  wconv_t<<<dim3(32, 64), B256, 0, stream>>>(w2, W2aT, 2048, 1024);
  wconv_t<<<dim3(32, 64), B256, 0, stream>>>(w2 + 2048 * 1024, W2bT, 2048, 1024);

  // x1 = LN1(x) -> bf16
  ln_k<<<16384, B256, 0, stream>>>(x, nullptr, ln1g, ln1b, nullptr, X1);

  // QKV = x1 @ [wq|wk|wv]   (grid 64 x 12 = 768 blocks)
  gemm256<0><<<dim3(768), B512, LDS, stream>>>(X1, WQKVT, QKV, nullptr,
                                               3072, 1024);

  // attention + scramble -> o_mixed (reuses X1 region)
  attn_k<<<4096, B256, 0, stream>>>(QKV, X1);

  // o2 = o_mixed @ wo -> f32 into d_out   (64 x 4 = 256 blocks)
  gemm256<1><<<dim3(256), B512, LDS, stream>>>(X1, WOT, out, nullptr,
                                               1024, 1024);

  // q2 = LN1(o2 + x): f32 in-place in d_out, bf16 copy in Q2B
  ln_k<<<16384, B256, 0, stream>>>(out, x, ln1g, ln1b, out, Q2B);

  // FFN half A  (W1: 64 x 8 = 512 blocks; W2: 256 blocks)
  gemm256<2><<<dim3(512), B512, LDS, stream>>>(Q2B, W1T, Hbuf, b1,
                                               2048, 1024);
  gemm256<4><<<dim3(256), B512, LDS, stream>>>(Hbuf, W2aT, out, nullptr,
                                               1024, 2048);

  // FFN half B
  gemm256<2><<<dim3(512), B512, LDS, stream>>>(Q2B, W1T + 2048 * 1024, Hbuf,
                                               b1 + 2048, 2048, 1024);
  gemm256<4><<<dim3(256), B512, LDS, stream>>>(Hbuf, W2bT, out, b2,
                                               1024, 2048);

  // out = LN2(y) in-place
  ln_k<<<16384, B256, 0, stream>>>(out, nullptr, ln2g, ln2b, out, nullptr);
}